// Round 6
// baseline (249.848 us; speedup 1.0000x reference)
//
#include <hip/hip_runtime.h>

// Multi-head self-attention, B=16 N=1024 D=768 H=12 DH=64.
// fp32 I/O, bf16 MFMA internally.
// K0: convert W (q,k,v) to bf16 once.
// K1: KV projection -> K[b,h][key][d] and Vt[b,h][e][key] (pre-transposed).
// K2: fused Q-projection + flash attention: 256 threads = 4 waves x 64 q-rows
//     (block = 256 q-rows); BARRIER-FREE main loop with K/V fragments loaded
//     directly from global (L1/L2); LDS only for P round-trip; max-free
//     softmax (exp2), deferred row-sum; XCD-swizzled grid.

#define NH 12
#define DHEAD 64
#define BB 16
#define NSEQ 1024
#define DMODEL 768
#define LSTR 72   // padded LDS row stride (u16 elems)
#define QSCALE 0.18033688f   // 0.125 * log2(e)

typedef unsigned short u16;
typedef unsigned int u32;
typedef u16 u16x8 __attribute__((ext_vector_type(8)));
typedef u16 u16x4 __attribute__((ext_vector_type(4)));
typedef __bf16 bf16x8 __attribute__((ext_vector_type(8)));
typedef float f32x4 __attribute__((ext_vector_type(4)));

union Frag { u16x8 u; bf16x8 b; };

__device__ __forceinline__ float fast_exp2(float x) {
#if __has_builtin(__builtin_amdgcn_exp2f)
    return __builtin_amdgcn_exp2f(x);
#else
    return exp2f(x);
#endif
}

__device__ __forceinline__ u16 f2bf(float f) {
    union { __bf16 h; u16 u; } c; c.h = (__bf16)f; return c.u;
}

__device__ __forceinline__ u16x8 cvt8(const float* __restrict__ p) {
    f32x4 a = *(const f32x4*)p;
    f32x4 b = *(const f32x4*)(p + 4);
    Frag r;
    r.b[0] = (__bf16)a[0]; r.b[1] = (__bf16)a[1]; r.b[2] = (__bf16)a[2]; r.b[3] = (__bf16)a[3];
    r.b[4] = (__bf16)b[0]; r.b[5] = (__bf16)b[1]; r.b[6] = (__bf16)b[2]; r.b[7] = (__bf16)b[3];
    return r.u;
}

// ---------------------------------------------------------------------------
// Kernel 0: convert Wq/Wk/Wv (3 x 12 x 64 x 64 fp32) to bf16 once.
// Wb layout: [m][h][e][d], m=0:q 1:k 2:v.
// ---------------------------------------------------------------------------
__global__ __launch_bounds__(256) void wcvt_kernel(
    const float* __restrict__ Wq, const float* __restrict__ Wk,
    const float* __restrict__ Wv, u16* __restrict__ Wb)
{
    const int bx = blockIdx.x;
    const int m = bx / 24;
    const int off = (bx % 24) * 2048 + threadIdx.x * 8;
    const float* srcs[3] = { Wq, Wk, Wv };
    *(u16x8*)(Wb + m * 49152 + off) = cvt8(srcs[m] + off);
}

// ---------------------------------------------------------------------------
// Kernel 1: KV projection, 128 tokens x 1 head per block (R5 structure).
// K = x Wk^T via K^T = Wk x^T -> scratch -> u16x8 stores to K[b,h][key][d].
// V = x Wv^T directly: C m=key n=e -> b64 stores to Vt[b,h][e][key].
// ---------------------------------------------------------------------------
__global__ __launch_bounds__(256) void kv_kernel(
    const float* __restrict__ x,                  // [B,N,768] fp32
    const u16*  __restrict__ Wb,
    const float* __restrict__ bk, const float* __restrict__ bv,
    u16* __restrict__ Ko,                         // [B,H,N,64] bf16
    u16* __restrict__ Vt)                         // [B,H,64,N] bf16
{
    __shared__ __align__(16) u16 w_lds[2][64 * LSTR];
    __shared__ __align__(16) u16 x_lds[128 * LSTR];

    const int bid = blockIdx.x;
    const int h     = bid % NH;
    const int chunk = (bid / NH) & 7;
    const int b     = bid / (NH * 8);

    const int t = threadIdx.x, lane = t & 63, wave = t >> 6;
    const int qd = lane >> 4, lm = lane & 15;

    {
        const int row = t >> 2, d0 = (t & 3) * 16;
#pragma unroll
        for (int m = 0; m < 2; m++) {
            const u16* s = Wb + (1 + m) * 49152 + h * 4096 + row * 64 + d0;
            *(u16x8*)&w_lds[m][row * LSTR + d0]     = *(const u16x8*)s;
            *(u16x8*)&w_lds[m][row * LSTR + d0 + 8] = *(const u16x8*)(s + 8);
        }
        const int xr = t >> 1, xd = (t & 1) * 32;
        const float* s = x + ((size_t)(b * NSEQ + chunk * 128 + xr)) * DMODEL + h * DHEAD + xd;
#pragma unroll
        for (int i = 0; i < 4; i++)
            *(u16x8*)&x_lds[xr * LSTR + xd + i * 8] = cvt8(s + i * 8);
    }
    __syncthreads();

    Frag xfrag[2][2];
#pragma unroll
    for (int mt = 0; mt < 2; mt++)
#pragma unroll
        for (int kk = 0; kk < 2; kk++)
            xfrag[mt][kk].u = *(const u16x8*)&x_lds[(wave * 32 + mt * 16 + lm) * LSTR + kk * 32 + qd * 8];

    u16* tx = &x_lds[wave * 32 * LSTR];
    const int key_base = chunk * 128 + wave * 32;

    // ---- K path ----
#pragma unroll
    for (int et = 0; et < 4; et++) {
        Frag wfrag[2];
#pragma unroll
        for (int kk = 0; kk < 2; kk++)
            wfrag[kk].u = *(const u16x8*)&w_lds[0][(et * 16 + lm) * LSTR + kk * 32 + qd * 8];
        f32x4 acc0 = {0.f,0.f,0.f,0.f}, acc1 = {0.f,0.f,0.f,0.f};
#pragma unroll
        for (int kk = 0; kk < 2; kk++) {
            acc0 = __builtin_amdgcn_mfma_f32_16x16x32_bf16(wfrag[kk].b, xfrag[0][kk].b, acc0, 0, 0, 0);
            acc1 = __builtin_amdgcn_mfma_f32_16x16x32_bf16(wfrag[kk].b, xfrag[1][kk].b, acc1, 0, 0, 0);
        }
        f32x4 b4 = *(const f32x4*)&bk[h * DHEAD + et * 16 + qd * 4];
        u16x4 o0, o1;
#pragma unroll
        for (int r = 0; r < 4; r++) {
            o0[r] = f2bf(acc0[r] + b4[r]);
            o1[r] = f2bf(acc1[r] + b4[r]);
        }
        *(u16x4*)&tx[lm * LSTR + et * 16 + qd * 4]        = o0;
        *(u16x4*)&tx[(16 + lm) * LSTR + et * 16 + qd * 4] = o1;
    }
    {
        const size_t base_out = ((size_t)(b * NH + h) * NSEQ + key_base) * DHEAD;
#pragma unroll
        for (int j = 0; j < 4; j++) {
            const int row = j * 8 + (lane >> 3), col = (lane & 7) * 8;
            u16x8 v = *(const u16x8*)&tx[row * LSTR + col];
            *(u16x8*)(Ko + base_out + (size_t)row * DHEAD + col) = v;
        }
    }

    // ---- V path -> Vt[e][key] via b64 stores ----
    const size_t vt_base = ((size_t)(b * NH + h)) * DHEAD * NSEQ;
#pragma unroll
    for (int et = 0; et < 4; et++) {
        Frag wvfrag[2];
#pragma unroll
        for (int kk = 0; kk < 2; kk++)
            wvfrag[kk].u = *(const u16x8*)&w_lds[1][(et * 16 + lm) * LSTR + kk * 32 + qd * 8];
        const float bvv = bv[h * DHEAD + et * 16 + lm];
#pragma unroll
        for (int mt = 0; mt < 2; mt++) {
            f32x4 acc = {0.f,0.f,0.f,0.f};
#pragma unroll
            for (int kk = 0; kk < 2; kk++)
                acc = __builtin_amdgcn_mfma_f32_16x16x32_bf16(xfrag[mt][kk].b, wvfrag[kk].b, acc, 0, 0, 0);
            u16x4 o;
#pragma unroll
            for (int r = 0; r < 4; r++) o[r] = f2bf(acc[r] + bvv);
            *(u16x4*)(Vt + vt_base + (size_t)(et * 16 + lm) * NSEQ + key_base + mt * 16 + qd * 4) = o;
        }
    }
}

// ---------------------------------------------------------------------------
// Kernel 2: fused Q-projection + flash attention.
// grid = (N/256)*B*H = 768 blocks x 256 threads (4 waves x 64 q-rows).
// bid = qt*192 + bh  ->  all 4 qt-blocks of one (b,h) share bid%8 (same XCD).
// Main loop is barrier-free: K/V frags loaded directly from global.
// ---------------------------------------------------------------------------
__global__ __launch_bounds__(256, 2) void attn_kernel(
    const float* __restrict__ x, const u16* __restrict__ Wb,
    const float* __restrict__ bq,
    const u16* __restrict__ K, const u16* __restrict__ Vt,
    float* __restrict__ out)   // [B,N,768] fp32
{
    __shared__ __align__(16) u16 wq_lds[64 * LSTR];      // 9.2 KB
    __shared__ __align__(16) u16 xbuf[64 * LSTR];        // 9.2 KB
    __shared__ __align__(16) u16 p_lds[4][16 * LSTR];    // 9.2 KB

    const int bid = blockIdx.x;
    const int bh = bid % 192;          // qt stride 192 == 0 mod 8 -> same XCD
    const int qt = bid / 192;          // 0..3 (256-token chunks)
    const int h = bh % NH, b = bh / NH;

    const int t = threadIdx.x, lane = t & 63, wave = t >> 6;
    const int qd = lane >> 4, lm = lane & 15;
    const size_t bh_off = (size_t)bh * NSEQ * DHEAD;
    const int tb = qt * 256;

    // ---- stage Wq ----
    {
        const int row = t >> 2, d0 = (t & 3) * 16;
        const u16* wq = Wb + h * 4096 + row * 64 + d0;
        *(u16x8*)&wq_lds[row * LSTR + d0]     = *(const u16x8*)wq;
        *(u16x8*)&wq_lds[row * LSTR + d0 + 8] = *(const u16x8*)(wq + 8);
    }

    // ---- Q phase: chunk c (64 tokens) staged; wave c computes its qfrags ----
    Frag qfrag[4][2];   // B-operand rows [q][e]
#pragma unroll 1
    for (int c = 0; c < 4; c++) {
        __syncthreads();   // previous chunk consumed (and Wq staged, c=0)
        {
            const int row = t >> 2, d0 = (t & 3) * 16;
            const float* xs = x + ((size_t)(b * NSEQ + tb + c * 64 + row)) * DMODEL + h * DHEAD + d0;
            *(u16x8*)&xbuf[row * LSTR + d0]     = cvt8(xs);
            *(u16x8*)&xbuf[row * LSTR + d0 + 8] = cvt8(xs + 8);
        }
        __syncthreads();
        if (wave == c) {
#pragma unroll
            for (int mtl = 0; mtl < 4; mtl++) {
                Frag xB[2];
#pragma unroll
                for (int kk = 0; kk < 2; kk++)
                    xB[kk].u = *(const u16x8*)&xbuf[(mtl * 16 + lm) * LSTR + kk * 32 + qd * 8];
#pragma unroll
                for (int et = 0; et < 4; et++) {
                    Frag wqA[2];
#pragma unroll
                    for (int kk = 0; kk < 2; kk++)
                        wqA[kk].u = *(const u16x8*)&wq_lds[(et * 16 + lm) * LSTR + kk * 32 + qd * 8];
                    f32x4 acc = {0.f,0.f,0.f,0.f};
#pragma unroll
                    for (int kk = 0; kk < 2; kk++)
                        acc = __builtin_amdgcn_mfma_f32_16x16x32_bf16(wqA[kk].b, xB[kk].b, acc, 0, 0, 0);
                    f32x4 b4 = *(const f32x4*)&bq[h * DHEAD + et * 16 + qd * 4];
                    u16x4 o;
#pragma unroll
                    for (int r = 0; r < 4; r++) o[r] = f2bf((acc[r] + b4[r]) * QSCALE);
                    *(u16x4*)&p_lds[wave][lm * LSTR + et * 16 + qd * 4] = o;
                }
#pragma unroll
                for (int kk = 0; kk < 2; kk++)
                    qfrag[mtl][kk].u = *(const u16x8*)&p_lds[wave][lm * LSTR + kk * 32 + qd * 8];
            }
        }
    }

    f32x4 o_acc[4][4] = {};
    f32x4 rsum = {0.f, 0.f, 0.f, 0.f};

    const u16* kb = K  + bh_off;
    const u16* vb = Vt + bh_off;

    // ---- barrier-free main loop over 16 key-tiles of 64 ----
#pragma unroll 1
    for (int it = 0; it < NSEQ / 64; it++) {
        // K frags (A-operand, [key][d]) and V frags (B-operand, [e][key])
        // straight from global — L1/L2 hits, no staging, no barriers.
        Frag kfrag[4][2], vfrag[4][2];
#pragma unroll
        for (int kt = 0; kt < 4; kt++)
#pragma unroll
            for (int kk = 0; kk < 2; kk++)
                kfrag[kt][kk].u = *(const u16x8*)(kb + (size_t)(it * 64 + kt * 16 + lm) * DHEAD + kk * 32 + qd * 8);
#pragma unroll
        for (int dt = 0; dt < 4; dt++)
#pragma unroll
            for (int kk = 0; kk < 2; kk++)
                vfrag[dt][kk].u = *(const u16x8*)(vb + (size_t)(dt * 16 + lm) * NSEQ + it * 64 + kk * 32 + qd * 8);

        // ---- S^T = K Q^T per mt; exp2; P -> p_lds -> pfrag ----
        Frag pfrag[4][2];
#pragma unroll
        for (int mt = 0; mt < 4; mt++) {
            f32x4 st[4];
#pragma unroll
            for (int kt = 0; kt < 4; kt++) {
                f32x4 a = {0.f,0.f,0.f,0.f};
#pragma unroll
                for (int kk = 0; kk < 2; kk++)
                    a = __builtin_amdgcn_mfma_f32_16x16x32_bf16(kfrag[kt][kk].b, qfrag[mt][kk].b, a, 0, 0, 0);
                st[kt] = a;
            }
            float rs = 0.f;
#pragma unroll
            for (int kt = 0; kt < 4; kt++) {
                u16x4 pk;
#pragma unroll
                for (int r = 0; r < 4; r++) {
                    float p = fast_exp2(st[kt][r]);
                    rs += p;
                    pk[r] = f2bf(p);
                }
                *(u16x4*)&p_lds[wave][lm * LSTR + kt * 16 + qd * 4] = pk;
            }
            rsum[mt] += rs;
#pragma unroll
            for (int kk = 0; kk < 2; kk++)
                pfrag[mt][kk].u = *(const u16x8*)&p_lds[wave][lm * LSTR + kk * 32 + qd * 8];
        }

        // ---- O += P V ----
#pragma unroll
        for (int dt = 0; dt < 4; dt++)
#pragma unroll
            for (int kk = 0; kk < 2; kk++)
#pragma unroll
                for (int mt = 0; mt < 4; mt++)
                    o_acc[mt][dt] = __builtin_amdgcn_mfma_f32_16x16x32_bf16(pfrag[mt][kk].b, vfrag[dt][kk].b, o_acc[mt][dt], 0, 0, 0);
    }

    // ---- epilogue ----
#pragma unroll
    for (int mt = 0; mt < 4; mt++) {
        float s = rsum[mt];
        s += __shfl_xor(s, 16);
        s += __shfl_xor(s, 32);
        float inv = 1.f / s;
        float inv4[4];
#pragma unroll
        for (int r = 0; r < 4; r++) inv4[r] = __shfl(inv, qd * 4 + r);
#pragma unroll
        for (int dt = 0; dt < 4; dt++) {
            const int e = dt * 16 + lm;
#pragma unroll
            for (int r = 0; r < 4; r++) {
                const int n_tok = tb + wave * 64 + mt * 16 + qd * 4 + r;
                out[((size_t)(b * NSEQ + n_tok)) * DMODEL + h * DHEAD + e] =
                    o_acc[mt][dt][r] * inv4[r];
            }
        }
    }
}

extern "C" void kernel_launch(void* const* d_in, const int* in_sizes, int n_in,
                              void* d_out, int out_size, void* d_ws, size_t ws_size,
                              hipStream_t stream) {
    const float* x  = (const float*)d_in[0];
    const float* Wq = (const float*)d_in[1];
    const float* Wk = (const float*)d_in[2];
    const float* Wv = (const float*)d_in[3];
    const float* bq = (const float*)d_in[4];
    const float* bk = (const float*)d_in[5];
    const float* bv = (const float*)d_in[6];
    float* out = (float*)d_out;

    const size_t KV_ELEMS = (size_t)BB * NH * NSEQ * DHEAD;  // 12,582,912
    u16* Kw  = (u16*)d_ws;
    u16* Vtw = Kw + KV_ELEMS;
    u16* Wb  = Vtw + KV_ELEMS;

    wcvt_kernel<<<72, 256, 0, stream>>>(Wq, Wk, Wv, Wb);
    kv_kernel<<<BB * 8 * NH, 256, 0, stream>>>(x, Wb, bk, bv, Kw, Vtw);
    attn_kernel<<<(NSEQ / 256) * BB * NH, 256, 0, stream>>>(x, Wb, bq, Kw, Vtw, out);
}

// Round 7
// 186.367 us; speedup vs baseline: 1.3406x; 1.3406x over previous
//
#include <hip/hip_runtime.h>

// Multi-head self-attention, B=16 N=1024 D=768 H=12 DH=64.
// fp32 I/O, bf16 MFMA internally.
// K0: convert W (q,k,v) to bf16 once.
// K1: KV projection -> K[b,h][key][d] and Vt[b,h][e][key] (pre-transposed).
// K2: fused Q-projection + flash attention: 256 threads = 4 waves x 64 q-rows
//     (block = 256 q-rows); LDS-staged K/V tiles + register prefetch
//     (R4's latency-hiding, R6's direct-global regressed); barrier-free
//     per-wave Q phase; max-free softmax (exp2); XCD-swizzled grid.

#define NH 12
#define DHEAD 64
#define BB 16
#define NSEQ 1024
#define DMODEL 768
#define LSTR 72   // padded LDS row stride (u16 elems)
#define QSCALE 0.18033688f   // 0.125 * log2(e)

typedef unsigned short u16;
typedef unsigned int u32;
typedef u16 u16x8 __attribute__((ext_vector_type(8)));
typedef u16 u16x4 __attribute__((ext_vector_type(4)));
typedef __bf16 bf16x8 __attribute__((ext_vector_type(8)));
typedef float f32x4 __attribute__((ext_vector_type(4)));

union Frag { u16x8 u; bf16x8 b; };

__device__ __forceinline__ float fast_exp2(float x) {
#if __has_builtin(__builtin_amdgcn_exp2f)
    return __builtin_amdgcn_exp2f(x);
#else
    return exp2f(x);
#endif
}

__device__ __forceinline__ u16 f2bf(float f) {
    union { __bf16 h; u16 u; } c; c.h = (__bf16)f; return c.u;
}

__device__ __forceinline__ u16x8 cvt8(const float* __restrict__ p) {
    f32x4 a = *(const f32x4*)p;
    f32x4 b = *(const f32x4*)(p + 4);
    Frag r;
    r.b[0] = (__bf16)a[0]; r.b[1] = (__bf16)a[1]; r.b[2] = (__bf16)a[2]; r.b[3] = (__bf16)a[3];
    r.b[4] = (__bf16)b[0]; r.b[5] = (__bf16)b[1]; r.b[6] = (__bf16)b[2]; r.b[7] = (__bf16)b[3];
    return r.u;
}

// ---------------------------------------------------------------------------
// Kernel 0: convert Wq/Wk/Wv (3 x 12 x 64 x 64 fp32) to bf16 once.
// Wb layout: [m][h][e][d], m=0:q 1:k 2:v.
// ---------------------------------------------------------------------------
__global__ __launch_bounds__(256) void wcvt_kernel(
    const float* __restrict__ Wq, const float* __restrict__ Wk,
    const float* __restrict__ Wv, u16* __restrict__ Wb)
{
    const int bx = blockIdx.x;
    const int m = bx / 24;
    const int off = (bx % 24) * 2048 + threadIdx.x * 8;
    const float* srcs[3] = { Wq, Wk, Wv };
    *(u16x8*)(Wb + m * 49152 + off) = cvt8(srcs[m] + off);
}

// ---------------------------------------------------------------------------
// Kernel 1: KV projection, 128 tokens x 1 head per block.
// K = x Wk^T via K^T = Wk x^T -> scratch -> u16x8 stores to K[b,h][key][d].
// V = x Wv^T directly: C m=key n=e -> b64 stores to Vt[b,h][e][key].
// ---------------------------------------------------------------------------
__global__ __launch_bounds__(256) void kv_kernel(
    const float* __restrict__ x,                  // [B,N,768] fp32
    const u16*  __restrict__ Wb,
    const float* __restrict__ bk, const float* __restrict__ bv,
    u16* __restrict__ Ko,                         // [B,H,N,64] bf16
    u16* __restrict__ Vt)                         // [B,H,64,N] bf16
{
    __shared__ __align__(16) u16 w_lds[2][64 * LSTR];
    __shared__ __align__(16) u16 x_lds[128 * LSTR];

    const int bid = blockIdx.x;
    const int h     = bid % NH;
    const int chunk = (bid / NH) & 7;
    const int b     = bid / (NH * 8);

    const int t = threadIdx.x, lane = t & 63, wave = t >> 6;
    const int qd = lane >> 4, lm = lane & 15;

    {
        const int row = t >> 2, d0 = (t & 3) * 16;
#pragma unroll
        for (int m = 0; m < 2; m++) {
            const u16* s = Wb + (1 + m) * 49152 + h * 4096 + row * 64 + d0;
            *(u16x8*)&w_lds[m][row * LSTR + d0]     = *(const u16x8*)s;
            *(u16x8*)&w_lds[m][row * LSTR + d0 + 8] = *(const u16x8*)(s + 8);
        }
        const int xr = t >> 1, xd = (t & 1) * 32;
        const float* s = x + ((size_t)(b * NSEQ + chunk * 128 + xr)) * DMODEL + h * DHEAD + xd;
#pragma unroll
        for (int i = 0; i < 4; i++)
            *(u16x8*)&x_lds[xr * LSTR + xd + i * 8] = cvt8(s + i * 8);
    }
    __syncthreads();

    Frag xfrag[2][2];
#pragma unroll
    for (int mt = 0; mt < 2; mt++)
#pragma unroll
        for (int kk = 0; kk < 2; kk++)
            xfrag[mt][kk].u = *(const u16x8*)&x_lds[(wave * 32 + mt * 16 + lm) * LSTR + kk * 32 + qd * 8];

    u16* tx = &x_lds[wave * 32 * LSTR];
    const int key_base = chunk * 128 + wave * 32;

    // ---- K path ----
#pragma unroll
    for (int et = 0; et < 4; et++) {
        Frag wfrag[2];
#pragma unroll
        for (int kk = 0; kk < 2; kk++)
            wfrag[kk].u = *(const u16x8*)&w_lds[0][(et * 16 + lm) * LSTR + kk * 32 + qd * 8];
        f32x4 acc0 = {0.f,0.f,0.f,0.f}, acc1 = {0.f,0.f,0.f,0.f};
#pragma unroll
        for (int kk = 0; kk < 2; kk++) {
            acc0 = __builtin_amdgcn_mfma_f32_16x16x32_bf16(wfrag[kk].b, xfrag[0][kk].b, acc0, 0, 0, 0);
            acc1 = __builtin_amdgcn_mfma_f32_16x16x32_bf16(wfrag[kk].b, xfrag[1][kk].b, acc1, 0, 0, 0);
        }
        f32x4 b4 = *(const f32x4*)&bk[h * DHEAD + et * 16 + qd * 4];
        u16x4 o0, o1;
#pragma unroll
        for (int r = 0; r < 4; r++) {
            o0[r] = f2bf(acc0[r] + b4[r]);
            o1[r] = f2bf(acc1[r] + b4[r]);
        }
        *(u16x4*)&tx[lm * LSTR + et * 16 + qd * 4]        = o0;
        *(u16x4*)&tx[(16 + lm) * LSTR + et * 16 + qd * 4] = o1;
    }
    {
        const size_t base_out = ((size_t)(b * NH + h) * NSEQ + key_base) * DHEAD;
#pragma unroll
        for (int j = 0; j < 4; j++) {
            const int row = j * 8 + (lane >> 3), col = (lane & 7) * 8;
            u16x8 v = *(const u16x8*)&tx[row * LSTR + col];
            *(u16x8*)(Ko + base_out + (size_t)row * DHEAD + col) = v;
        }
    }

    // ---- V path -> Vt[e][key] via b64 stores ----
    const size_t vt_base = ((size_t)(b * NH + h)) * DHEAD * NSEQ;
#pragma unroll
    for (int et = 0; et < 4; et++) {
        Frag wvfrag[2];
#pragma unroll
        for (int kk = 0; kk < 2; kk++)
            wvfrag[kk].u = *(const u16x8*)&w_lds[1][(et * 16 + lm) * LSTR + kk * 32 + qd * 8];
        const float bvv = bv[h * DHEAD + et * 16 + lm];
#pragma unroll
        for (int mt = 0; mt < 2; mt++) {
            f32x4 acc = {0.f,0.f,0.f,0.f};
#pragma unroll
            for (int kk = 0; kk < 2; kk++)
                acc = __builtin_amdgcn_mfma_f32_16x16x32_bf16(xfrag[mt][kk].b, wvfrag[kk].b, acc, 0, 0, 0);
            u16x4 o;
#pragma unroll
            for (int r = 0; r < 4; r++) o[r] = f2bf(acc[r] + bvv);
            *(u16x4*)(Vt + vt_base + (size_t)(et * 16 + lm) * NSEQ + key_base + mt * 16 + qd * 4) = o;
        }
    }
}

// ---------------------------------------------------------------------------
// Kernel 2: fused Q-projection + flash attention.
// grid = (N/256)*B*H = 768 blocks x 256 threads (4 waves x 64 q-rows).
// bid = qt*192 + bh -> all 4 qt-blocks of one (b,h) on the same XCD.
// ---------------------------------------------------------------------------
__global__ __launch_bounds__(256, 2) void attn_kernel(
    const float* __restrict__ x, const u16* __restrict__ Wb,
    const float* __restrict__ bq,
    const u16* __restrict__ K, const u16* __restrict__ Vt,
    float* __restrict__ out)   // [B,N,768] fp32
{
    __shared__ __align__(16) u16 k_lds[64 * LSTR];       // Wq during Q-phase, then K tiles
    __shared__ __align__(16) u16 vt_lds[64 * LSTR];      // V tiles [e][key]
    __shared__ __align__(16) u16 p_lds[4][16 * LSTR];    // per-wave x/Q/P scratch

    const int bid = blockIdx.x;
    const int bh = bid % 192;          // qt stride 192 == 0 mod 8 -> same XCD
    const int qt = bid / 192;          // 0..3 (256-token chunks)
    const int h = bh % NH, b = bh / NH;

    const int t = threadIdx.x, lane = t & 63, wave = t >> 6;
    const int qd = lane >> 4, lm = lane & 15;
    const size_t bh_off = (size_t)bh * NSEQ * DHEAD;
    const int tb = qt * 256;

    // ---- stage Wq into k_lds (overwritten by first K tile later) ----
    {
        const int row = t >> 2, d0 = (t & 3) * 16;
        const u16* wq = Wb + h * 4096 + row * 64 + d0;
        *(u16x8*)&k_lds[row * LSTR + d0]     = *(const u16x8*)wq;
        *(u16x8*)&k_lds[row * LSTR + d0 + 8] = *(const u16x8*)(wq + 8);
    }
    __syncthreads();

    // ---- barrier-free per-wave Q phase: wave w owns tokens tb+w*64.. ----
    // Per 16-row sub-chunk: stage x -> p_lds[wave], read xB frags, MFMA
    // Q^T = Wq x^T, write Q -> p_lds[wave], read qfrag. Same-wave DS is
    // in-order, so no synchronization needed.
    Frag qfrag[4][2];   // B-operand rows [q][e]
    {
        const int xrow = lane >> 2, xd0 = (lane & 3) * 16;
#pragma unroll
        for (int mtl = 0; mtl < 4; mtl++) {
            const float* xs = x + ((size_t)(b * NSEQ + tb + wave * 64 + mtl * 16 + xrow)) * DMODEL
                              + h * DHEAD + xd0;
            *(u16x8*)&p_lds[wave][xrow * LSTR + xd0]     = cvt8(xs);
            *(u16x8*)&p_lds[wave][xrow * LSTR + xd0 + 8] = cvt8(xs + 8);
            Frag xB[2];
#pragma unroll
            for (int kk = 0; kk < 2; kk++)
                xB[kk].u = *(const u16x8*)&p_lds[wave][lm * LSTR + kk * 32 + qd * 8];
#pragma unroll
            for (int et = 0; et < 4; et++) {
                Frag wqA[2];
#pragma unroll
                for (int kk = 0; kk < 2; kk++)
                    wqA[kk].u = *(const u16x8*)&k_lds[(et * 16 + lm) * LSTR + kk * 32 + qd * 8];
                f32x4 acc = {0.f,0.f,0.f,0.f};
#pragma unroll
                for (int kk = 0; kk < 2; kk++)
                    acc = __builtin_amdgcn_mfma_f32_16x16x32_bf16(wqA[kk].b, xB[kk].b, acc, 0, 0, 0);
                f32x4 b4 = *(const f32x4*)&bq[h * DHEAD + et * 16 + qd * 4];
                u16x4 o;
#pragma unroll
                for (int r = 0; r < 4; r++) o[r] = f2bf((acc[r] + b4[r]) * QSCALE);
                // C m=e (qd*4+r consecutive), n=q=lm -> [q][e]
                *(u16x4*)&p_lds[wave][lm * LSTR + et * 16 + qd * 4] = o;
            }
#pragma unroll
            for (int kk = 0; kk < 2; kk++)
                qfrag[mtl][kk].u = *(const u16x8*)&p_lds[wave][lm * LSTR + kk * 32 + qd * 8];
        }
    }

    f32x4 o_acc[4][4] = {};
    f32x4 rsum = {0.f, 0.f, 0.f, 0.f};

    const u16* kb = K  + bh_off;
    const u16* vb = Vt + bh_off;

    // staging map: thread covers one row (key for K, e for V), 16 elems
    const int srow = t >> 2, sd0 = (t & 3) * 16;

    // prefetch tile 0
    u16x8 kreg0, kreg1, vreg0, vreg1;
    {
        const u16* sk = kb + (size_t)srow * DHEAD + sd0;
        kreg0 = *(const u16x8*)sk; kreg1 = *(const u16x8*)(sk + 8);
        const u16* sv = vb + (size_t)srow * NSEQ + sd0;
        vreg0 = *(const u16x8*)sv; vreg1 = *(const u16x8*)(sv + 8);
    }

    // ---- main loop over 16 key-tiles of 64 ----
#pragma unroll 1
    for (int it = 0; it < NSEQ / 64; it++) {
        __syncthreads();   // previous compute done (and Q-phase Wq reads, it=0)
        *(u16x8*)&k_lds[srow * LSTR + sd0]      = kreg0;
        *(u16x8*)&k_lds[srow * LSTR + sd0 + 8]  = kreg1;
        *(u16x8*)&vt_lds[srow * LSTR + sd0]     = vreg0;
        *(u16x8*)&vt_lds[srow * LSTR + sd0 + 8] = vreg1;
        __syncthreads();

        if (it + 1 < NSEQ / 64) {
            const u16* sk = kb + (size_t)((it + 1) * 64 + srow) * DHEAD + sd0;
            kreg0 = *(const u16x8*)sk; kreg1 = *(const u16x8*)(sk + 8);
            const u16* sv = vb + (size_t)srow * NSEQ + (it + 1) * 64 + sd0;
            vreg0 = *(const u16x8*)sv; vreg1 = *(const u16x8*)(sv + 8);
        }

        // kfrag: A-operand rows [key][d]
        Frag kfrag[4][2];
#pragma unroll
        for (int kt = 0; kt < 4; kt++)
#pragma unroll
            for (int kk = 0; kk < 2; kk++)
                kfrag[kt][kk].u = *(const u16x8*)&k_lds[(kt * 16 + lm) * LSTR + kk * 32 + qd * 8];

        // ---- S^T = K Q^T per mt; exp2; P -> p_lds -> pfrag ----
        Frag pfrag[4][2];
#pragma unroll
        for (int mt = 0; mt < 4; mt++) {
            f32x4 st[4];
#pragma unroll
            for (int kt = 0; kt < 4; kt++) {
                f32x4 a = {0.f,0.f,0.f,0.f};
#pragma unroll
                for (int kk = 0; kk < 2; kk++)
                    a = __builtin_amdgcn_mfma_f32_16x16x32_bf16(kfrag[kt][kk].b, qfrag[mt][kk].b, a, 0, 0, 0);
                st[kt] = a;
            }
            float rs = 0.f;
#pragma unroll
            for (int kt = 0; kt < 4; kt++) {
                u16x4 pk;
#pragma unroll
                for (int r = 0; r < 4; r++) {
                    float p = fast_exp2(st[kt][r]);
                    rs += p;
                    pk[r] = f2bf(p);
                }
                // key = kt*16 + qd*4 + r (consecutive), q-local = lm
                *(u16x4*)&p_lds[wave][lm * LSTR + kt * 16 + qd * 4] = pk;
            }
            rsum[mt] += rs;
#pragma unroll
            for (int kk = 0; kk < 2; kk++)
                pfrag[mt][kk].u = *(const u16x8*)&p_lds[wave][lm * LSTR + kk * 32 + qd * 8];
        }

        // ---- O += P V : vfrag read once per dt, used by all 4 mt ----
#pragma unroll
        for (int dt = 0; dt < 4; dt++) {
            Frag vfrag[2];
#pragma unroll
            for (int kk = 0; kk < 2; kk++)
                vfrag[kk].u = *(const u16x8*)&vt_lds[(dt * 16 + lm) * LSTR + kk * 32 + qd * 8];
#pragma unroll
            for (int kk = 0; kk < 2; kk++)
#pragma unroll
                for (int mt = 0; mt < 4; mt++)
                    o_acc[mt][dt] = __builtin_amdgcn_mfma_f32_16x16x32_bf16(pfrag[mt][kk].b, vfrag[kk].b, o_acc[mt][dt], 0, 0, 0);
        }
    }

    // ---- epilogue ----
#pragma unroll
    for (int mt = 0; mt < 4; mt++) {
        float s = rsum[mt];
        s += __shfl_xor(s, 16);
        s += __shfl_xor(s, 32);
        float inv = 1.f / s;
        float inv4[4];
#pragma unroll
        for (int r = 0; r < 4; r++) inv4[r] = __shfl(inv, qd * 4 + r);
#pragma unroll
        for (int dt = 0; dt < 4; dt++) {
            const int e = dt * 16 + lm;
#pragma unroll
            for (int r = 0; r < 4; r++) {
                const int n_tok = tb + wave * 64 + mt * 16 + qd * 4 + r;
                out[((size_t)(b * NSEQ + n_tok)) * DMODEL + h * DHEAD + e] =
                    o_acc[mt][dt][r] * inv4[r];
            }
        }
    }
}

extern "C" void kernel_launch(void* const* d_in, const int* in_sizes, int n_in,
                              void* d_out, int out_size, void* d_ws, size_t ws_size,
                              hipStream_t stream) {
    const float* x  = (const float*)d_in[0];
    const float* Wq = (const float*)d_in[1];
    const float* Wk = (const float*)d_in[2];
    const float* Wv = (const float*)d_in[3];
    const float* bq = (const float*)d_in[4];
    const float* bk = (const float*)d_in[5];
    const float* bv = (const float*)d_in[6];
    float* out = (float*)d_out;

    const size_t KV_ELEMS = (size_t)BB * NH * NSEQ * DHEAD;  // 12,582,912
    u16* Kw  = (u16*)d_ws;
    u16* Vtw = Kw + KV_ELEMS;
    u16* Wb  = Vtw + KV_ELEMS;

    wcvt_kernel<<<72, 256, 0, stream>>>(Wq, Wk, Wv, Wb);
    kv_kernel<<<BB * 8 * NH, 256, 0, stream>>>(x, Wb, bk, bv, Kw, Vtw);
    attn_kernel<<<(NSEQ / 256) * BB * NH, 256, 0, stream>>>(x, Wb, bq, Kw, Vtw, out);
}